// Round 17
// baseline (462.864 us; speedup 1.0000x reference)
//
#include <hip/hip_runtime.h>
#include <hip/hip_fp16.h>

#define NNODES 100000
#define NBUCK 391                 // ceil(100000/256) buckets of 256 nodes (dst>>8)
#define NB_CHUNK 256              // edge chunks for counting sort
#define NC (NBUCK * NB_CHUNK)     // count-matrix size = 100096
#define SCAN_ELEMS 1024           // counts entries per scanw block (256 threads x 4)

typedef _Float16 f16x8 __attribute__((ext_vector_type(8)));
typedef float    f32x4 __attribute__((ext_vector_type(4)));

// ---------------- K0: W-frag prep + sniffer + bsum zero + cbase[NC]=E ----------------
__global__ __launch_bounds__(256) void prep_kernel(const float* __restrict__ W1,
                                                   const float* __restrict__ W2,
                                                   const int* __restrict__ raw,
                                                   __half* __restrict__ wf1,
                                                   __half* __restrict__ wf2,
                                                   int* __restrict__ flag,
                                                   int* __restrict__ bsum,
                                                   int* __restrict__ cbase, int E) {
    int b = blockIdx.x;
    if (b < 64) {
        int flat = b * 256 + threadIdx.x;         // W1 frags
        int j  = flat & 7;
        int l  = (flat >> 3) & 63;
        int nb = (flat >> 9) & 3;
        int kc = flat >> 11;
        int k  = kc * 32 + ((l >> 4) << 3) + j;
        int nc = nb * 16 + (l & 15);
        wf1[flat] = __float2half(W1[k * 64 + nc]);
    } else if (b < 96) {
        int flat = (b - 64) * 256 + threadIdx.x;  // W2 frags
        int j  = flat & 7;
        int l  = (flat >> 3) & 63;
        int nb = (flat >> 9) & 7;
        int kc = flat >> 12;
        int k  = kc * 32 + ((l >> 4) << 3) + j;
        int nc = nb * 16 + (l & 15);
        wf2[flat] = __float2half(W2[k * 128 + nc]);
    } else {
        __shared__ int cnt;
        if (threadIdx.x == 0) cnt = 0;
        if (threadIdx.x < 128) bsum[threadIdx.x] = 0;   // zeroed every call (graph-safe)
        if (threadIdx.x == 128) cbase[NC] = E;
        __syncthreads();
        if (threadIdx.x < 100) {
            if (raw[2 * threadIdx.x + 1] == 0) atomicAdd(&cnt, 1);
        }
        __syncthreads();
        if (threadIdx.x == 0) *flag = (cnt > 50) ? 1 : 0;
    }
}

// ---------------- K1: fused [convert+count(+bsum)  ||  gemm1 MFMA] ----------------
// Chunk blocks also accumulate per-4-bucket totals into bsum (replaces scan_partial).
__global__ __launch_bounds__(256) void convert_gemm1_kernel(const int* __restrict__ raw,
                                                            int* __restrict__ src32,
                                                            int* __restrict__ dst32,
                                                            int* __restrict__ counts,
                                                            int* __restrict__ bsum,
                                                            int E, int CE,
                                                            const int* __restrict__ flag,
                                                            const float* __restrict__ x,
                                                            const __half* __restrict__ wf,
                                                            __half* __restrict__ H, int M) {
    __shared__ __align__(16) char smem[64 * 264 * 2];   // union: hist[391] | xs[64][264]
    int bid = blockIdx.x;
    if (bid < NB_CHUNK) {
        int* hist = (int*)smem;
        for (int i = threadIdx.x; i < NBUCK; i += 256) hist[i] = 0;
        __syncthreads();
        int isI64 = *flag;
        int beg = bid * CE;
        int end = beg + CE; if (end > E) end = E;
        const int2* raw2 = reinterpret_cast<const int2*>(raw);
        for (int e = beg + (int)threadIdx.x; e < end; e += 256) {
            int s, d;
            if (isI64) {
                s = raw2[e].x;          // raw[2e]   (low word)
                d = raw2[E + e].x;      // raw[2E+2e]
            } else {
                s = raw[e];
                d = raw[E + e];
            }
            src32[e] = s;
            dst32[e] = d;
            atomicAdd(&hist[d >> 8], 1);              // LDS atomic
        }
        __syncthreads();
        for (int k = threadIdx.x; k < NBUCK; k += 256) {
            int hv = hist[k];
            counts[k * NB_CHUNK + bid] = hv;          // bucket-major for linear scan
            if (hv) atomicAdd(&bsum[k >> 2], hv);     // per-scanw-block totals
        }
    } else {
        __half (*xs)[264] = (__half(*)[264])smem;
        int tid = threadIdx.x;
        int bm = (bid - NB_CHUNK) * 64;
        const float4* x4 = reinterpret_cast<const float4*>(x);
#pragma unroll
        for (int i = 0; i < 16; ++i) {
            int lin = i * 256 + tid;
            int row = lin >> 6;
            int c4  = lin & 63;
            int gr = bm + row; if (gr >= M) gr = M - 1;
            float4 v = x4[(size_t)gr * 64 + c4];
            __half* dst = &xs[row][c4 * 4];
            dst[0] = __float2half(v.x); dst[1] = __float2half(v.y);
            dst[2] = __float2half(v.z); dst[3] = __float2half(v.w);
        }
        __syncthreads();
        int w = tid >> 6;          // wave 0..3 -> rows bm+w*16 .. +15
        int l = tid & 63;
        int lrow = l & 15;
        int lk   = l >> 4;
        const f16x8* wf8 = reinterpret_cast<const f16x8*>(wf);
        f32x4 acc[4] = {};
#pragma unroll
        for (int kc = 0; kc < 8; ++kc) {
            f16x8 a = *reinterpret_cast<const f16x8*>(&xs[w * 16 + lrow][kc * 32 + lk * 8]);
#pragma unroll
            for (int nb = 0; nb < 4; ++nb) {
                f16x8 bfr = wf8[(kc * 4 + nb) * 64 + l];
                acc[nb] = __builtin_amdgcn_mfma_f32_16x16x32_f16(a, bfr, acc[nb], 0, 0, 0);
            }
        }
#pragma unroll
        for (int nb = 0; nb < 4; ++nb)
#pragma unroll
            for (int r = 0; r < 4; ++r) {
                int row = bm + w * 16 + lk * 4 + r;
                if (row < M) H[(size_t)row * 64 + nb * 16 + lrow] = __float2half(acc[nb][r]);
            }
    }
}

// ---------------- scanw: counts -> cbase in ONE launch ----------------
// Each block redundantly scans the 128-entry bsum (LDS) for its global offset,
// then exclusive-scans its 1024 counts entries (replaces scan_partials+scan_write).
__global__ __launch_bounds__(256) void scanw_kernel(const int* __restrict__ counts,
                                                    const int* __restrict__ bsum,
                                                    int* __restrict__ cbase, int n) {
    __shared__ int ts[256];
    __shared__ int bs[256];
    int tid = threadIdx.x;
    bs[tid] = (tid < 128) ? bsum[tid] : 0;
    __syncthreads();
    for (int d = 1; d < 128; d <<= 1) {           // inclusive scan of bsum
        int v = (tid >= d) ? bs[tid - d] : 0;
        __syncthreads();
        bs[tid] += v;
        __syncthreads();
    }
    int boff = (blockIdx.x == 0) ? 0 : bs[blockIdx.x - 1];

    int base = blockIdx.x * SCAN_ELEMS + tid * 4;
    int v0 = 0, v1 = 0, v2 = 0, v3 = 0;
    if (base + 3 < n) {
        int4 v = *reinterpret_cast<const int4*>(&counts[base]);
        v0 = v.x; v1 = v.y; v2 = v.z; v3 = v.w;
    } else {
        if (base < n)     v0 = counts[base];
        if (base + 1 < n) v1 = counts[base + 1];
        if (base + 2 < n) v2 = counts[base + 2];
    }
    ts[tid] = v0 + v1 + v2 + v3;
    __syncthreads();
    for (int d = 1; d < 256; d <<= 1) {
        int t = (tid >= d) ? ts[tid - d] : 0;
        __syncthreads();
        ts[tid] += t;
        __syncthreads();
    }
    int run = boff + ((tid == 0) ? 0 : ts[tid - 1]);
    if (base < n)     { cbase[base] = run;     run += v0; }
    if (base + 1 < n) { cbase[base + 1] = run; run += v1; }
    if (base + 2 < n) { cbase[base + 2] = run; run += v2; }
    if (base + 3 < n) { cbase[base + 3] = run; }
}

// ---------------- counting sort pass 2: scatter (packed: src | (d&255)<<24) ----------------
__global__ __launch_bounds__(256) void scatter_kernel(const int* __restrict__ src32,
                                                      const int* __restrict__ dst32,
                                                      const int* __restrict__ cbase,
                                                      int* __restrict__ cw,
                                                      int E, int CE) {
    __shared__ int cur[NBUCK];
    int b = blockIdx.x;
    for (int k = threadIdx.x; k < NBUCK; k += 256)
        cur[k] = cbase[k * NB_CHUNK + b];
    __syncthreads();
    int beg = b * CE;
    int end = beg + CE; if (end > E) end = E;
    for (int e = beg + (int)threadIdx.x; e < end; e += 256) {
        int s = __builtin_nontemporal_load(&src32[e]);   // streaming, don't pollute L2
        int d = __builtin_nontemporal_load(&dst32[e]);
        int pos = atomicAdd(&cur[d >> 8], 1);     // LDS atomic
        cw[pos] = s | ((d & 255) << 24);          // single-CU contiguous run per bucket
    }
}

// ---------------- bucketfin: histdeg + dinv + ptr (bucket-local scan) + col fill ----------------
__global__ __launch_bounds__(256) void bucketfin_kernel(const int* __restrict__ cw,
                                                        const int* __restrict__ cbase,
                                                        int* __restrict__ ptr,
                                                        float* __restrict__ dinv,
                                                        int* __restrict__ col,
                                                        int n, int E) {
    __shared__ int hist[256];
    __shared__ int sc[256];
    int tid = threadIdx.x;
    int k = blockIdx.x;
    hist[tid] = 0;
    __syncthreads();
    int beg = cbase[k * NB_CHUNK];
    int end = cbase[(k + 1) * NB_CHUNK];
    for (int e = beg + tid; e < end; e += 256)
        atomicAdd(&hist[(cw[e] >> 24) & 255], 1); // LDS atomic
    __syncthreads();
    int dg = hist[tid];
    sc[tid] = dg;
    __syncthreads();
    for (int d = 1; d < 256; d <<= 1) {           // Hillis-Steele inclusive scan
        int t = (tid >= d) ? sc[tid - d] : 0;
        __syncthreads();
        sc[tid] += t;
        __syncthreads();
    }
    int p0 = beg + sc[tid] - dg;                  // bucket base + exclusive prefix
    int i = (k << 8) + tid;
    if (i < n) {
        ptr[i] = p0;
        dinv[i] = rsqrtf((float)(dg + 1));        // +1 self loop; always > 0
    }
    if (k == NBUCK - 1 && tid == 0) ptr[n] = E;
    __syncthreads();
    hist[tid] = p0;                               // reuse as cursor
    __syncthreads();
    for (int e = beg + tid; e < end; e += 256) {
        int v = cw[e];
        int pos = atomicAdd(&hist[(v >> 24) & 255], 1);
        col[pos] = v & 0x00FFFFFF;
    }
}

// ---------------- aggregation: fp16 gathers, per-edge weight dinv[col] ----------------
__global__ __launch_bounds__(256) void aggregate_kernel(const __half* __restrict__ h,
                                                        const int* __restrict__ ptr,
                                                        const int* __restrict__ col,
                                                        const float* __restrict__ dinv,
                                                        const float* __restrict__ bias,
                                                        __half* __restrict__ out, int n,
                                                        int relu) {
    int node = (blockIdx.x << 2) + (threadIdx.x >> 6);
    if (node >= n) return;
    int lane = threadIdx.x & 63;
    int g  = lane >> 3;               // edge-group 0..7
    int fl = (lane & 7) << 3;         // feature base: 0,8,...,56
    float acc[8] = {};
    int pend = ptr[node + 1];
    int p = ptr[node] + g;
    for (; p + 8 < pend; p += 16) {   // unroll 2: 16 edges in flight per wave
        int c0 = __builtin_nontemporal_load(&col[p]);        // col is single-use stream
        int c1 = __builtin_nontemporal_load(&col[p + 8]);
        uint4 r0 = *reinterpret_cast<const uint4*>(&h[(size_t)c0 * 64 + fl]);
        uint4 r1 = *reinterpret_cast<const uint4*>(&h[(size_t)c1 * 64 + fl]);
        float w0 = dinv[c0], w1 = dinv[c1];
        const unsigned* u0 = &r0.x;
        const unsigned* u1 = &r1.x;
#pragma unroll
        for (int k = 0; k < 4; ++k) {
            float2 f0 = __half22float2(*reinterpret_cast<const __half2*>(&u0[k]));
            float2 f1 = __half22float2(*reinterpret_cast<const __half2*>(&u1[k]));
            acc[2 * k]     = fmaf(w0, f0.x, acc[2 * k]);
            acc[2 * k + 1] = fmaf(w0, f0.y, acc[2 * k + 1]);
            acc[2 * k]     = fmaf(w1, f1.x, acc[2 * k]);
            acc[2 * k + 1] = fmaf(w1, f1.y, acc[2 * k + 1]);
        }
    }
    if (p < pend) {
        int c0 = __builtin_nontemporal_load(&col[p]);
        uint4 r0 = *reinterpret_cast<const uint4*>(&h[(size_t)c0 * 64 + fl]);
        float w0 = dinv[c0];
        const unsigned* u0 = &r0.x;
#pragma unroll
        for (int k = 0; k < 4; ++k) {
            float2 f0 = __half22float2(*reinterpret_cast<const __half2*>(&u0[k]));
            acc[2 * k]     = fmaf(w0, f0.x, acc[2 * k]);
            acc[2 * k + 1] = fmaf(w0, f0.y, acc[2 * k + 1]);
        }
    }
#pragma unroll
    for (int j = 0; j < 8; ++j) {
        acc[j] += __shfl_xor(acc[j], 8, 64);
        acc[j] += __shfl_xor(acc[j], 16, 64);
        acc[j] += __shfl_xor(acc[j], 32, 64);
    }
    if (g == 0) {                     // lanes 0..7 own the epilogue
        float di = dinv[node];
        uint4 sv = *reinterpret_cast<const uint4*>(&h[(size_t)node * 64 + fl]);
        const unsigned* su = &sv.x;
        float v[8];
#pragma unroll
        for (int k = 0; k < 4; ++k) {
            float2 f = __half22float2(*reinterpret_cast<const __half2*>(&su[k]));
            v[2 * k]     = fmaf(di, f.x, acc[2 * k]) * di;
            v[2 * k + 1] = fmaf(di, f.y, acc[2 * k + 1]) * di;
        }
        if (bias) {
            float4 b0 = *reinterpret_cast<const float4*>(&bias[fl]);
            float4 b1 = *reinterpret_cast<const float4*>(&bias[fl + 4]);
            v[0] += b0.x; v[1] += b0.y; v[2] += b0.z; v[3] += b0.w;
            v[4] += b1.x; v[5] += b1.y; v[6] += b1.z; v[7] += b1.w;
        }
        if (relu) {
#pragma unroll
            for (int j = 0; j < 8; ++j) v[j] = fmaxf(v[j], 0.f);
        }
        __half hv[8];
#pragma unroll
        for (int j = 0; j < 8; ++j) hv[j] = __float2half(v[j]);
        *reinterpret_cast<uint4*>(&out[(size_t)node * 64 + fl]) =
            *reinterpret_cast<const uint4*>(hv);
    }
}

// ---------------- GEMM2 via MFMA: fp16 [M,64] @ [64,128] + b -> fp32 [M,128] ----------------
__global__ __launch_bounds__(256) void gemm2_kernel(const __half* __restrict__ A,
                                                    const __half* __restrict__ wf,
                                                    const float* __restrict__ bias,
                                                    float* __restrict__ out, int M) {
    int tid = threadIdx.x;
    int w = tid >> 6;
    int l = tid & 63;
    int lrow = l & 15;
    int lk   = l >> 4;
    int base = blockIdx.x * 64 + w * 16;
    int arow = base + lrow; if (arow >= M) arow = M - 1;
    f16x8 a0 = *reinterpret_cast<const f16x8*>(&A[(size_t)arow * 64 + lk * 8]);
    f16x8 a1 = *reinterpret_cast<const f16x8*>(&A[(size_t)arow * 64 + 32 + lk * 8]);
    const f16x8* wf8 = reinterpret_cast<const f16x8*>(wf);
    f32x4 acc[8] = {};
#pragma unroll
    for (int nb = 0; nb < 8; ++nb) {
        acc[nb] = __builtin_amdgcn_mfma_f32_16x16x32_f16(a0, wf8[nb * 64 + l], acc[nb], 0, 0, 0);
        acc[nb] = __builtin_amdgcn_mfma_f32_16x16x32_f16(a1, wf8[(8 + nb) * 64 + l], acc[nb], 0, 0, 0);
    }
#pragma unroll
    for (int nb = 0; nb < 8; ++nb) {
        float bv = bias[nb * 16 + lrow];
#pragma unroll
        for (int r = 0; r < 4; ++r) {
            int row = base + lk * 4 + r;
            if (row < M) out[(size_t)row * 128 + nb * 16 + lrow] = acc[nb][r] + bv;
        }
    }
}

extern "C" void kernel_launch(void* const* d_in, const int* in_sizes, int n_in,
                              void* d_out, int out_size, void* d_ws, size_t ws_size,
                              hipStream_t stream) {
    const float* x  = (const float*)d_in[0];
    const int*   ei = (const int*)d_in[1];
    const float* W1 = (const float*)d_in[2];
    const float* b1 = (const float*)d_in[3];
    const float* W2 = (const float*)d_in[4];
    const float* b2 = (const float*)d_in[5];
    float* out = (float*)d_out;
    const int n = NNODES;
    const int E = in_sizes[1] / 2;
    const int CE = (E + NB_CHUNK - 1) / NB_CHUNK;

    char* w = (char*)d_ws;
    auto alloc = [&](size_t bytes) {
        char* p = w;
        w += (bytes + 255) & ~(size_t)255;
        return p;
    };
    int*    flag   = (int*)   alloc(4);
    int*    src32  = (int*)   alloc((size_t)E * 4);
    int*    dst32  = (int*)   alloc((size_t)E * 4);
    int*    counts = (int*)   alloc((size_t)NC * 4);
    int*    cbase  = (int*)   alloc((size_t)(NC + 1) * 4);
    float*  dinv   = (float*) alloc((size_t)n * 4);
    int*    ptr    = (int*)   alloc((size_t)(n + 1) * 4);
    int*    bsum   = (int*)   alloc(128 * 4);
    int*    cw     = (int*)   alloc((size_t)E * 4);
    int*    col    = (int*)   alloc((size_t)E * 4);
    __half* wfrag  = (__half*)alloc(16384 * 2);
    __half* wfrag2 = (__half*)alloc(8192 * 2);
    __half* H1     = (__half*)alloc((size_t)n * 64 * 2);
    __half* h1     = (__half*)alloc((size_t)n * 64 * 2);
    __half* A2     = (__half*)alloc((size_t)n * 64 * 2);

    int sbC = (NC + SCAN_ELEMS - 1) / SCAN_ELEMS;   // 98 scanw blocks
    int g1b = (n + 63) / 64;                        // 1563 gemm1 blocks

    prep_kernel<<<97, 256, 0, stream>>>(W1, W2, ei, wfrag, wfrag2, flag, bsum, cbase, E);
    convert_gemm1_kernel<<<NB_CHUNK + g1b, 256, 0, stream>>>(
        ei, src32, dst32, counts, bsum, E, CE, flag, x, wfrag, H1, n);
    scanw_kernel<<<sbC, 256, 0, stream>>>(counts, bsum, cbase, NC);
    scatter_kernel<<<NB_CHUNK, 256, 0, stream>>>(src32, dst32, cbase, cw, E, CE);
    bucketfin_kernel<<<NBUCK, 256, 0, stream>>>(cw, cbase, ptr, dinv, col, n, E);

    aggregate_kernel<<<(n + 3) / 4, 256, 0, stream>>>(H1, ptr, col, dinv, b1, h1, n, 1);
    aggregate_kernel<<<(n + 3) / 4, 256, 0, stream>>>(h1, ptr, col, dinv, nullptr, A2, n, 0);
    gemm2_kernel<<<(n + 63) / 64, 256, 0, stream>>>(A2, wfrag2, b2, out, n);
}

// Round 18
// 207.670 us; speedup vs baseline: 2.2289x; 2.2289x over previous
//
#include <hip/hip_runtime.h>
#include <hip/hip_fp16.h>

#define NNODES 100000
#define NBUCK 391                 // ceil(100000/256) buckets of 256 nodes (dst>>8)
#define NB_CHUNK 256              // edge chunks for counting sort
#define NC (NBUCK * NB_CHUNK)     // count-matrix size = 100096
#define SCAN_ELEMS 1024           // counts entries per scanw block (256 threads x 4)

typedef _Float16 f16x8 __attribute__((ext_vector_type(8)));
typedef float    f32x4 __attribute__((ext_vector_type(4)));

// ---------------- K0: W-frag prep + sniffer + cbase[NC]=E ----------------
__global__ __launch_bounds__(256) void prep_kernel(const float* __restrict__ W1,
                                                   const float* __restrict__ W2,
                                                   const int* __restrict__ raw,
                                                   __half* __restrict__ wf1,
                                                   __half* __restrict__ wf2,
                                                   int* __restrict__ flag,
                                                   int* __restrict__ cbase, int E) {
    int b = blockIdx.x;
    if (b < 64) {
        int flat = b * 256 + threadIdx.x;         // W1 frags
        int j  = flat & 7;
        int l  = (flat >> 3) & 63;
        int nb = (flat >> 9) & 3;
        int kc = flat >> 11;
        int k  = kc * 32 + ((l >> 4) << 3) + j;
        int nc = nb * 16 + (l & 15);
        wf1[flat] = __float2half(W1[k * 64 + nc]);
    } else if (b < 96) {
        int flat = (b - 64) * 256 + threadIdx.x;  // W2 frags
        int j  = flat & 7;
        int l  = (flat >> 3) & 63;
        int nb = (flat >> 9) & 7;
        int kc = flat >> 12;
        int k  = kc * 32 + ((l >> 4) << 3) + j;
        int nc = nb * 16 + (l & 15);
        wf2[flat] = __float2half(W2[k * 128 + nc]);
    } else {
        __shared__ int cnt;
        if (threadIdx.x == 0) cnt = 0;
        if (threadIdx.x == 128) cbase[NC] = E;    // bucketfin's last-bucket end
        __syncthreads();
        if (threadIdx.x < 100) {
            if (raw[2 * threadIdx.x + 1] == 0) atomicAdd(&cnt, 1);
        }
        __syncthreads();
        if (threadIdx.x == 0) *flag = (cnt > 50) ? 1 : 0;
    }
}

// ---------------- K1: fused [convert+count  ||  gemm1 MFMA] ----------------
// NO global atomics (R17 lesson: ~100k atomics on 98 words serialized ~300us).
__global__ __launch_bounds__(256) void convert_gemm1_kernel(const int* __restrict__ raw,
                                                            int* __restrict__ src32,
                                                            int* __restrict__ dst32,
                                                            int* __restrict__ counts,
                                                            int E, int CE,
                                                            const int* __restrict__ flag,
                                                            const float* __restrict__ x,
                                                            const __half* __restrict__ wf,
                                                            __half* __restrict__ H, int M) {
    __shared__ __align__(16) char smem[64 * 264 * 2];   // union: hist[391] | xs[64][264]
    int bid = blockIdx.x;
    if (bid < NB_CHUNK) {
        int* hist = (int*)smem;
        for (int i = threadIdx.x; i < NBUCK; i += 256) hist[i] = 0;
        __syncthreads();
        int isI64 = *flag;
        int beg = bid * CE;
        int end = beg + CE; if (end > E) end = E;
        const int2* raw2 = reinterpret_cast<const int2*>(raw);
        for (int e = beg + (int)threadIdx.x; e < end; e += 256) {
            int s, d;
            if (isI64) {
                s = raw2[e].x;          // raw[2e]   (low word)
                d = raw2[E + e].x;      // raw[2E+2e]
            } else {
                s = raw[e];
                d = raw[E + e];
            }
            src32[e] = s;
            dst32[e] = d;
            atomicAdd(&hist[d >> 8], 1);              // LDS atomic
        }
        __syncthreads();
        for (int k = threadIdx.x; k < NBUCK; k += 256)
            counts[k * NB_CHUNK + bid] = hist[k];     // bucket-major for linear scan
    } else {
        __half (*xs)[264] = (__half(*)[264])smem;
        int tid = threadIdx.x;
        int bm = (bid - NB_CHUNK) * 64;
        const float4* x4 = reinterpret_cast<const float4*>(x);
#pragma unroll
        for (int i = 0; i < 16; ++i) {
            int lin = i * 256 + tid;
            int row = lin >> 6;
            int c4  = lin & 63;
            int gr = bm + row; if (gr >= M) gr = M - 1;
            float4 v = x4[(size_t)gr * 64 + c4];
            __half* dst = &xs[row][c4 * 4];
            dst[0] = __float2half(v.x); dst[1] = __float2half(v.y);
            dst[2] = __float2half(v.z); dst[3] = __float2half(v.w);
        }
        __syncthreads();
        int w = tid >> 6;          // wave 0..3 -> rows bm+w*16 .. +15
        int l = tid & 63;
        int lrow = l & 15;
        int lk   = l >> 4;
        const f16x8* wf8 = reinterpret_cast<const f16x8*>(wf);
        f32x4 acc[4] = {};
#pragma unroll
        for (int kc = 0; kc < 8; ++kc) {
            f16x8 a = *reinterpret_cast<const f16x8*>(&xs[w * 16 + lrow][kc * 32 + lk * 8]);
#pragma unroll
            for (int nb = 0; nb < 4; ++nb) {
                f16x8 bfr = wf8[(kc * 4 + nb) * 64 + l];
                acc[nb] = __builtin_amdgcn_mfma_f32_16x16x32_f16(a, bfr, acc[nb], 0, 0, 0);
            }
        }
#pragma unroll
        for (int nb = 0; nb < 4; ++nb)
#pragma unroll
            for (int r = 0; r < 4; ++r) {
                int row = bm + w * 16 + lk * 4 + r;
                if (row < M) H[(size_t)row * 64 + nb * 16 + lrow] = __float2half(acc[nb][r]);
            }
    }
}

// ---------------- scanw: counts -> cbase, ONE launch, no global atomics ----------------
// Each block computes its global offset by directly summing counts[0 .. bid*1024)
// (redundant-parallel prefix: ~19.5MB total of L2-resident reads across 98 blocks),
// then exclusive-scans its own 1024 entries.
__global__ __launch_bounds__(256) void scanw_kernel(const int* __restrict__ counts,
                                                    int* __restrict__ cbase, int n) {
    __shared__ int ts[256];
    __shared__ int ws[4];
    int tid = threadIdx.x;
    int m = blockIdx.x * SCAN_ELEMS;              // prefix region [0, m)
    int s = 0;
    for (int i = tid * 4; i < m; i += 1024) {
        int4 v = *reinterpret_cast<const int4*>(&counts[i]);
        s += v.x + v.y + v.z + v.w;
    }
#pragma unroll
    for (int d = 32; d; d >>= 1) s += __shfl_down(s, d, 64);
    if ((tid & 63) == 0) ws[tid >> 6] = s;
    __syncthreads();
    int boff = ws[0] + ws[1] + ws[2] + ws[3];     // uniform across block

    int base = m + tid * 4;
    int v0 = 0, v1 = 0, v2 = 0, v3 = 0;
    if (base + 3 < n) {
        int4 v = *reinterpret_cast<const int4*>(&counts[base]);
        v0 = v.x; v1 = v.y; v2 = v.z; v3 = v.w;
    } else {
        if (base < n)     v0 = counts[base];
        if (base + 1 < n) v1 = counts[base + 1];
        if (base + 2 < n) v2 = counts[base + 2];
    }
    ts[tid] = v0 + v1 + v2 + v3;
    __syncthreads();
    for (int d = 1; d < 256; d <<= 1) {
        int t = (tid >= d) ? ts[tid - d] : 0;
        __syncthreads();
        ts[tid] += t;
        __syncthreads();
    }
    int run = boff + ((tid == 0) ? 0 : ts[tid - 1]);
    if (base < n)     { cbase[base] = run;     run += v0; }
    if (base + 1 < n) { cbase[base + 1] = run; run += v1; }
    if (base + 2 < n) { cbase[base + 2] = run; run += v2; }
    if (base + 3 < n) { cbase[base + 3] = run; }
}

// ---------------- counting sort pass 2: scatter (packed: src | (d&255)<<24) ----------------
__global__ __launch_bounds__(256) void scatter_kernel(const int* __restrict__ src32,
                                                      const int* __restrict__ dst32,
                                                      const int* __restrict__ cbase,
                                                      int* __restrict__ cw,
                                                      int E, int CE) {
    __shared__ int cur[NBUCK];
    int b = blockIdx.x;
    for (int k = threadIdx.x; k < NBUCK; k += 256)
        cur[k] = cbase[k * NB_CHUNK + b];
    __syncthreads();
    int beg = b * CE;
    int end = beg + CE; if (end > E) end = E;
    for (int e = beg + (int)threadIdx.x; e < end; e += 256) {
        int s = __builtin_nontemporal_load(&src32[e]);   // streaming, don't pollute L2
        int d = __builtin_nontemporal_load(&dst32[e]);
        int pos = atomicAdd(&cur[d >> 8], 1);     // LDS atomic
        cw[pos] = s | ((d & 255) << 24);          // single-CU contiguous run per bucket
    }
}

// ---------------- bucketfin: histdeg + dinv + ptr (bucket-local scan) + col fill ----------------
__global__ __launch_bounds__(256) void bucketfin_kernel(const int* __restrict__ cw,
                                                        const int* __restrict__ cbase,
                                                        int* __restrict__ ptr,
                                                        float* __restrict__ dinv,
                                                        int* __restrict__ col,
                                                        int n, int E) {
    __shared__ int hist[256];
    __shared__ int sc[256];
    int tid = threadIdx.x;
    int k = blockIdx.x;
    hist[tid] = 0;
    __syncthreads();
    int beg = cbase[k * NB_CHUNK];
    int end = cbase[(k + 1) * NB_CHUNK];
    for (int e = beg + tid; e < end; e += 256)
        atomicAdd(&hist[(cw[e] >> 24) & 255], 1); // LDS atomic
    __syncthreads();
    int dg = hist[tid];
    sc[tid] = dg;
    __syncthreads();
    for (int d = 1; d < 256; d <<= 1) {           // Hillis-Steele inclusive scan
        int t = (tid >= d) ? sc[tid - d] : 0;
        __syncthreads();
        sc[tid] += t;
        __syncthreads();
    }
    int p0 = beg + sc[tid] - dg;                  // bucket base + exclusive prefix
    int i = (k << 8) + tid;
    if (i < n) {
        ptr[i] = p0;
        dinv[i] = rsqrtf((float)(dg + 1));        // +1 self loop; always > 0
    }
    if (k == NBUCK - 1 && tid == 0) ptr[n] = E;
    __syncthreads();
    hist[tid] = p0;                               // reuse as cursor
    __syncthreads();
    for (int e = beg + tid; e < end; e += 256) {
        int v = cw[e];
        int pos = atomicAdd(&hist[(v >> 24) & 255], 1);
        col[pos] = v & 0x00FFFFFF;
    }
}

// ---------------- aggregation: fp16 gathers, per-edge weight dinv[col] ----------------
__global__ __launch_bounds__(256) void aggregate_kernel(const __half* __restrict__ h,
                                                        const int* __restrict__ ptr,
                                                        const int* __restrict__ col,
                                                        const float* __restrict__ dinv,
                                                        const float* __restrict__ bias,
                                                        __half* __restrict__ out, int n,
                                                        int relu) {
    int node = (blockIdx.x << 2) + (threadIdx.x >> 6);
    if (node >= n) return;
    int lane = threadIdx.x & 63;
    int g  = lane >> 3;               // edge-group 0..7
    int fl = (lane & 7) << 3;         // feature base: 0,8,...,56
    float acc[8] = {};
    int pend = ptr[node + 1];
    int p = ptr[node] + g;
    for (; p + 8 < pend; p += 16) {   // unroll 2: 16 edges in flight per wave
        int c0 = __builtin_nontemporal_load(&col[p]);        // col is single-use stream
        int c1 = __builtin_nontemporal_load(&col[p + 8]);
        uint4 r0 = *reinterpret_cast<const uint4*>(&h[(size_t)c0 * 64 + fl]);
        uint4 r1 = *reinterpret_cast<const uint4*>(&h[(size_t)c1 * 64 + fl]);
        float w0 = dinv[c0], w1 = dinv[c1];
        const unsigned* u0 = &r0.x;
        const unsigned* u1 = &r1.x;
#pragma unroll
        for (int k = 0; k < 4; ++k) {
            float2 f0 = __half22float2(*reinterpret_cast<const __half2*>(&u0[k]));
            float2 f1 = __half22float2(*reinterpret_cast<const __half2*>(&u1[k]));
            acc[2 * k]     = fmaf(w0, f0.x, acc[2 * k]);
            acc[2 * k + 1] = fmaf(w0, f0.y, acc[2 * k + 1]);
            acc[2 * k]     = fmaf(w1, f1.x, acc[2 * k]);
            acc[2 * k + 1] = fmaf(w1, f1.y, acc[2 * k + 1]);
        }
    }
    if (p < pend) {
        int c0 = __builtin_nontemporal_load(&col[p]);
        uint4 r0 = *reinterpret_cast<const uint4*>(&h[(size_t)c0 * 64 + fl]);
        float w0 = dinv[c0];
        const unsigned* u0 = &r0.x;
#pragma unroll
        for (int k = 0; k < 4; ++k) {
            float2 f0 = __half22float2(*reinterpret_cast<const __half2*>(&u0[k]));
            acc[2 * k]     = fmaf(w0, f0.x, acc[2 * k]);
            acc[2 * k + 1] = fmaf(w0, f0.y, acc[2 * k + 1]);
        }
    }
#pragma unroll
    for (int j = 0; j < 8; ++j) {
        acc[j] += __shfl_xor(acc[j], 8, 64);
        acc[j] += __shfl_xor(acc[j], 16, 64);
        acc[j] += __shfl_xor(acc[j], 32, 64);
    }
    if (g == 0) {                     // lanes 0..7 own the epilogue
        float di = dinv[node];
        uint4 sv = *reinterpret_cast<const uint4*>(&h[(size_t)node * 64 + fl]);
        const unsigned* su = &sv.x;
        float v[8];
#pragma unroll
        for (int k = 0; k < 4; ++k) {
            float2 f = __half22float2(*reinterpret_cast<const __half2*>(&su[k]));
            v[2 * k]     = fmaf(di, f.x, acc[2 * k]) * di;
            v[2 * k + 1] = fmaf(di, f.y, acc[2 * k + 1]) * di;
        }
        if (bias) {
            float4 b0 = *reinterpret_cast<const float4*>(&bias[fl]);
            float4 b1 = *reinterpret_cast<const float4*>(&bias[fl + 4]);
            v[0] += b0.x; v[1] += b0.y; v[2] += b0.z; v[3] += b0.w;
            v[4] += b1.x; v[5] += b1.y; v[6] += b1.z; v[7] += b1.w;
        }
        if (relu) {
#pragma unroll
            for (int j = 0; j < 8; ++j) v[j] = fmaxf(v[j], 0.f);
        }
        __half hv[8];
#pragma unroll
        for (int j = 0; j < 8; ++j) hv[j] = __float2half(v[j]);
        *reinterpret_cast<uint4*>(&out[(size_t)node * 64 + fl]) =
            *reinterpret_cast<const uint4*>(hv);
    }
}

// ---------------- GEMM2 via MFMA: fp16 [M,64] @ [64,128] + b -> fp32 [M,128] ----------------
__global__ __launch_bounds__(256) void gemm2_kernel(const __half* __restrict__ A,
                                                    const __half* __restrict__ wf,
                                                    const float* __restrict__ bias,
                                                    float* __restrict__ out, int M) {
    int tid = threadIdx.x;
    int w = tid >> 6;
    int l = tid & 63;
    int lrow = l & 15;
    int lk   = l >> 4;
    int base = blockIdx.x * 64 + w * 16;
    int arow = base + lrow; if (arow >= M) arow = M - 1;
    f16x8 a0 = *reinterpret_cast<const f16x8*>(&A[(size_t)arow * 64 + lk * 8]);
    f16x8 a1 = *reinterpret_cast<const f16x8*>(&A[(size_t)arow * 64 + 32 + lk * 8]);
    const f16x8* wf8 = reinterpret_cast<const f16x8*>(wf);
    f32x4 acc[8] = {};
#pragma unroll
    for (int nb = 0; nb < 8; ++nb) {
        acc[nb] = __builtin_amdgcn_mfma_f32_16x16x32_f16(a0, wf8[nb * 64 + l], acc[nb], 0, 0, 0);
        acc[nb] = __builtin_amdgcn_mfma_f32_16x16x32_f16(a1, wf8[(8 + nb) * 64 + l], acc[nb], 0, 0, 0);
    }
#pragma unroll
    for (int nb = 0; nb < 8; ++nb) {
        float bv = bias[nb * 16 + lrow];
#pragma unroll
        for (int r = 0; r < 4; ++r) {
            int row = base + lk * 4 + r;
            if (row < M) out[(size_t)row * 128 + nb * 16 + lrow] = acc[nb][r] + bv;
        }
    }
}

extern "C" void kernel_launch(void* const* d_in, const int* in_sizes, int n_in,
                              void* d_out, int out_size, void* d_ws, size_t ws_size,
                              hipStream_t stream) {
    const float* x  = (const float*)d_in[0];
    const int*   ei = (const int*)d_in[1];
    const float* W1 = (const float*)d_in[2];
    const float* b1 = (const float*)d_in[3];
    const float* W2 = (const float*)d_in[4];
    const float* b2 = (const float*)d_in[5];
    float* out = (float*)d_out;
    const int n = NNODES;
    const int E = in_sizes[1] / 2;
    const int CE = (E + NB_CHUNK - 1) / NB_CHUNK;

    char* w = (char*)d_ws;
    auto alloc = [&](size_t bytes) {
        char* p = w;
        w += (bytes + 255) & ~(size_t)255;
        return p;
    };
    int*    flag   = (int*)   alloc(4);
    int*    src32  = (int*)   alloc((size_t)E * 4);
    int*    dst32  = (int*)   alloc((size_t)E * 4);
    int*    counts = (int*)   alloc((size_t)NC * 4);
    int*    cbase  = (int*)   alloc((size_t)(NC + 1) * 4);
    float*  dinv   = (float*) alloc((size_t)n * 4);
    int*    ptr    = (int*)   alloc((size_t)(n + 1) * 4);
    int*    cw     = (int*)   alloc((size_t)E * 4);
    int*    col    = (int*)   alloc((size_t)E * 4);
    __half* wfrag  = (__half*)alloc(16384 * 2);
    __half* wfrag2 = (__half*)alloc(8192 * 2);
    __half* H1     = (__half*)alloc((size_t)n * 64 * 2);
    __half* h1     = (__half*)alloc((size_t)n * 64 * 2);
    __half* A2     = (__half*)alloc((size_t)n * 64 * 2);

    int sbC = (NC + SCAN_ELEMS - 1) / SCAN_ELEMS;   // 98 scanw blocks
    int g1b = (n + 63) / 64;                        // 1563 gemm1 blocks

    prep_kernel<<<97, 256, 0, stream>>>(W1, W2, ei, wfrag, wfrag2, flag, cbase, E);
    convert_gemm1_kernel<<<NB_CHUNK + g1b, 256, 0, stream>>>(
        ei, src32, dst32, counts, E, CE, flag, x, wfrag, H1, n);
    scanw_kernel<<<sbC, 256, 0, stream>>>(counts, cbase, NC);
    scatter_kernel<<<NB_CHUNK, 256, 0, stream>>>(src32, dst32, cbase, cw, E, CE);
    bucketfin_kernel<<<NBUCK, 256, 0, stream>>>(cw, cbase, ptr, dinv, col, n, E);

    aggregate_kernel<<<(n + 3) / 4, 256, 0, stream>>>(H1, ptr, col, dinv, b1, h1, n, 1);
    aggregate_kernel<<<(n + 3) / 4, 256, 0, stream>>>(h1, ptr, col, dinv, nullptr, A2, n, 0);
    gemm2_kernel<<<(n + 63) / 64, 256, 0, stream>>>(A2, wfrag2, b2, out, n);
}

// Round 19
// 190.184 us; speedup vs baseline: 2.4338x; 1.0919x over previous
//
#include <hip/hip_runtime.h>
#include <hip/hip_fp16.h>

#define NNODES 100000
#define NBUCK 391                 // ceil(100000/256) buckets of 256 nodes (dst>>8)
#define NB_CHUNK 256              // edge chunks for counting sort
#define NC (NBUCK * NB_CHUNK)     // count-matrix size = 100096
#define SCAN_ELEMS 1024           // counts entries per scanw block (256 threads x 4)

typedef _Float16 f16x8 __attribute__((ext_vector_type(8)));
typedef float    f32x4 __attribute__((ext_vector_type(4)));

// ---------------- K0: W-frag prep + sniffer + cbase[NC]=E ----------------
__global__ __launch_bounds__(256) void prep_kernel(const float* __restrict__ W1,
                                                   const float* __restrict__ W2,
                                                   const int* __restrict__ raw,
                                                   __half* __restrict__ wf1,
                                                   __half* __restrict__ wf2,
                                                   int* __restrict__ flag,
                                                   int* __restrict__ cbase, int E) {
    int b = blockIdx.x;
    if (b < 64) {
        int flat = b * 256 + threadIdx.x;         // W1 frags
        int j  = flat & 7;
        int l  = (flat >> 3) & 63;
        int nb = (flat >> 9) & 3;
        int kc = flat >> 11;
        int k  = kc * 32 + ((l >> 4) << 3) + j;
        int nc = nb * 16 + (l & 15);
        wf1[flat] = __float2half(W1[k * 64 + nc]);
    } else if (b < 96) {
        int flat = (b - 64) * 256 + threadIdx.x;  // W2 frags
        int j  = flat & 7;
        int l  = (flat >> 3) & 63;
        int nb = (flat >> 9) & 7;
        int kc = flat >> 12;
        int k  = kc * 32 + ((l >> 4) << 3) + j;
        int nc = nb * 16 + (l & 15);
        wf2[flat] = __float2half(W2[k * 128 + nc]);
    } else {
        __shared__ int cnt;
        if (threadIdx.x == 0) cnt = 0;
        if (threadIdx.x == 128) cbase[NC] = E;    // bucketfin's last-bucket end
        __syncthreads();
        if (threadIdx.x < 100) {
            if (raw[2 * threadIdx.x + 1] == 0) atomicAdd(&cnt, 1);
        }
        __syncthreads();
        if (threadIdx.x == 0) *flag = (cnt > 50) ? 1 : 0;
    }
}

// ---------------- K1: fused [convert+count  ||  gemm1 MFMA] ----------------
// NO global atomics (R17 lesson: ~100k atomics on 98 words serialized ~300us).
__global__ __launch_bounds__(256) void convert_gemm1_kernel(const int* __restrict__ raw,
                                                            int* __restrict__ src32,
                                                            int* __restrict__ dst32,
                                                            int* __restrict__ counts,
                                                            int E, int CE,
                                                            const int* __restrict__ flag,
                                                            const float* __restrict__ x,
                                                            const __half* __restrict__ wf,
                                                            __half* __restrict__ H, int M) {
    __shared__ __align__(16) char smem[64 * 264 * 2];   // union: hist[391] | xs[64][264]
    int bid = blockIdx.x;
    if (bid < NB_CHUNK) {
        int* hist = (int*)smem;
        for (int i = threadIdx.x; i < NBUCK; i += 256) hist[i] = 0;
        __syncthreads();
        int isI64 = *flag;
        int beg = bid * CE;
        int end = beg + CE; if (end > E) end = E;
        const int2* raw2 = reinterpret_cast<const int2*>(raw);
        for (int e = beg + (int)threadIdx.x; e < end; e += 256) {
            int s, d;
            if (isI64) {
                s = raw2[e].x;          // raw[2e]   (low word)
                d = raw2[E + e].x;      // raw[2E+2e]
            } else {
                s = raw[e];
                d = raw[E + e];
            }
            src32[e] = s;
            dst32[e] = d;
            atomicAdd(&hist[d >> 8], 1);              // LDS atomic
        }
        __syncthreads();
        for (int k = threadIdx.x; k < NBUCK; k += 256)
            counts[k * NB_CHUNK + bid] = hist[k];     // bucket-major for linear scan
    } else {
        __half (*xs)[264] = (__half(*)[264])smem;
        int tid = threadIdx.x;
        int bm = (bid - NB_CHUNK) * 64;
        const float4* x4 = reinterpret_cast<const float4*>(x);
#pragma unroll
        for (int i = 0; i < 16; ++i) {
            int lin = i * 256 + tid;
            int row = lin >> 6;
            int c4  = lin & 63;
            int gr = bm + row; if (gr >= M) gr = M - 1;
            float4 v = x4[(size_t)gr * 64 + c4];
            __half* dst = &xs[row][c4 * 4];
            dst[0] = __float2half(v.x); dst[1] = __float2half(v.y);
            dst[2] = __float2half(v.z); dst[3] = __float2half(v.w);
        }
        __syncthreads();
        int w = tid >> 6;          // wave 0..3 -> rows bm+w*16 .. +15
        int l = tid & 63;
        int lrow = l & 15;
        int lk   = l >> 4;
        const f16x8* wf8 = reinterpret_cast<const f16x8*>(wf);
        f32x4 acc[4] = {};
#pragma unroll
        for (int kc = 0; kc < 8; ++kc) {
            f16x8 a = *reinterpret_cast<const f16x8*>(&xs[w * 16 + lrow][kc * 32 + lk * 8]);
#pragma unroll
            for (int nb = 0; nb < 4; ++nb) {
                f16x8 bfr = wf8[(kc * 4 + nb) * 64 + l];
                acc[nb] = __builtin_amdgcn_mfma_f32_16x16x32_f16(a, bfr, acc[nb], 0, 0, 0);
            }
        }
#pragma unroll
        for (int nb = 0; nb < 4; ++nb)
#pragma unroll
            for (int r = 0; r < 4; ++r) {
                int row = bm + w * 16 + lk * 4 + r;
                if (row < M) H[(size_t)row * 64 + nb * 16 + lrow] = __float2half(acc[nb][r]);
            }
    }
}

// ---------------- scanw: counts -> cbase, ONE launch, no global atomics ----------------
// Each block computes its global offset by directly summing counts[0 .. bid*1024)
// (redundant-parallel prefix: ~19.5MB total of L2-resident reads across 98 blocks),
// then exclusive-scans its own 1024 entries.
__global__ __launch_bounds__(256) void scanw_kernel(const int* __restrict__ counts,
                                                    int* __restrict__ cbase, int n) {
    __shared__ int ts[256];
    __shared__ int ws[4];
    int tid = threadIdx.x;
    int m = blockIdx.x * SCAN_ELEMS;              // prefix region [0, m)
    int s = 0;
    for (int i = tid * 4; i < m; i += 1024) {
        int4 v = *reinterpret_cast<const int4*>(&counts[i]);
        s += v.x + v.y + v.z + v.w;
    }
#pragma unroll
    for (int d = 32; d; d >>= 1) s += __shfl_down(s, d, 64);
    if ((tid & 63) == 0) ws[tid >> 6] = s;
    __syncthreads();
    int boff = ws[0] + ws[1] + ws[2] + ws[3];     // uniform across block

    int base = m + tid * 4;
    int v0 = 0, v1 = 0, v2 = 0, v3 = 0;
    if (base + 3 < n) {
        int4 v = *reinterpret_cast<const int4*>(&counts[base]);
        v0 = v.x; v1 = v.y; v2 = v.z; v3 = v.w;
    } else {
        if (base < n)     v0 = counts[base];
        if (base + 1 < n) v1 = counts[base + 1];
        if (base + 2 < n) v2 = counts[base + 2];
    }
    ts[tid] = v0 + v1 + v2 + v3;
    __syncthreads();
    for (int d = 1; d < 256; d <<= 1) {
        int t = (tid >= d) ? ts[tid - d] : 0;
        __syncthreads();
        ts[tid] += t;
        __syncthreads();
    }
    int run = boff + ((tid == 0) ? 0 : ts[tid - 1]);
    if (base < n)     { cbase[base] = run;     run += v0; }
    if (base + 1 < n) { cbase[base + 1] = run; run += v1; }
    if (base + 2 < n) { cbase[base + 2] = run; run += v2; }
    if (base + 3 < n) { cbase[base + 3] = run; }
}

// ---------------- counting sort pass 2: scatter (packed: src | (d&255)<<24) ----------------
__global__ __launch_bounds__(256) void scatter_kernel(const int* __restrict__ src32,
                                                      const int* __restrict__ dst32,
                                                      const int* __restrict__ cbase,
                                                      int* __restrict__ cw,
                                                      int E, int CE) {
    __shared__ int cur[NBUCK];
    int b = blockIdx.x;
    for (int k = threadIdx.x; k < NBUCK; k += 256)
        cur[k] = cbase[k * NB_CHUNK + b];
    __syncthreads();
    int beg = b * CE;
    int end = beg + CE; if (end > E) end = E;
    for (int e = beg + (int)threadIdx.x; e < end; e += 256) {
        int s = src32[e];                         // plain loads (NT hurt: R18 lesson)
        int d = dst32[e];
        int pos = atomicAdd(&cur[d >> 8], 1);     // LDS atomic
        cw[pos] = s | ((d & 255) << 24);          // single-CU contiguous run per bucket
    }
}

// ---------------- bucketfin: histdeg + dinv + ptr (bucket-local scan) + col fill ----------------
__global__ __launch_bounds__(256) void bucketfin_kernel(const int* __restrict__ cw,
                                                        const int* __restrict__ cbase,
                                                        int* __restrict__ ptr,
                                                        float* __restrict__ dinv,
                                                        int* __restrict__ col,
                                                        int n, int E) {
    __shared__ int hist[256];
    __shared__ int sc[256];
    int tid = threadIdx.x;
    int k = blockIdx.x;
    hist[tid] = 0;
    __syncthreads();
    int beg = cbase[k * NB_CHUNK];
    int end = cbase[(k + 1) * NB_CHUNK];
    for (int e = beg + tid; e < end; e += 256)
        atomicAdd(&hist[(cw[e] >> 24) & 255], 1); // LDS atomic
    __syncthreads();
    int dg = hist[tid];
    sc[tid] = dg;
    __syncthreads();
    for (int d = 1; d < 256; d <<= 1) {           // Hillis-Steele inclusive scan
        int t = (tid >= d) ? sc[tid - d] : 0;
        __syncthreads();
        sc[tid] += t;
        __syncthreads();
    }
    int p0 = beg + sc[tid] - dg;                  // bucket base + exclusive prefix
    int i = (k << 8) + tid;
    if (i < n) {
        ptr[i] = p0;
        dinv[i] = rsqrtf((float)(dg + 1));        // +1 self loop; always > 0
    }
    if (k == NBUCK - 1 && tid == 0) ptr[n] = E;
    __syncthreads();
    hist[tid] = p0;                               // reuse as cursor
    __syncthreads();
    for (int e = beg + tid; e < end; e += 256) {
        int v = cw[e];
        int pos = atomicAdd(&hist[(v >> 24) & 255], 1);
        col[pos] = v & 0x00FFFFFF;
    }
}

// ---------------- aggregation: fp16 gathers, per-edge weight dinv[col] ----------------
__global__ __launch_bounds__(256) void aggregate_kernel(const __half* __restrict__ h,
                                                        const int* __restrict__ ptr,
                                                        const int* __restrict__ col,
                                                        const float* __restrict__ dinv,
                                                        const float* __restrict__ bias,
                                                        __half* __restrict__ out, int n,
                                                        int relu) {
    int node = (blockIdx.x << 2) + (threadIdx.x >> 6);
    if (node >= n) return;
    int lane = threadIdx.x & 63;
    int g  = lane >> 3;               // edge-group 0..7
    int fl = (lane & 7) << 3;         // feature base: 0,8,...,56
    float acc[8] = {};
    int pend = ptr[node + 1];
    int p = ptr[node] + g;
    for (; p + 8 < pend; p += 16) {   // unroll 2: 16 edges in flight per wave
        int c0 = col[p];              // plain loads: col lines reused within wave (R18 lesson)
        int c1 = col[p + 8];
        uint4 r0 = *reinterpret_cast<const uint4*>(&h[(size_t)c0 * 64 + fl]);
        uint4 r1 = *reinterpret_cast<const uint4*>(&h[(size_t)c1 * 64 + fl]);
        float w0 = dinv[c0], w1 = dinv[c1];
        const unsigned* u0 = &r0.x;
        const unsigned* u1 = &r1.x;
#pragma unroll
        for (int k = 0; k < 4; ++k) {
            float2 f0 = __half22float2(*reinterpret_cast<const __half2*>(&u0[k]));
            float2 f1 = __half22float2(*reinterpret_cast<const __half2*>(&u1[k]));
            acc[2 * k]     = fmaf(w0, f0.x, acc[2 * k]);
            acc[2 * k + 1] = fmaf(w0, f0.y, acc[2 * k + 1]);
            acc[2 * k]     = fmaf(w1, f1.x, acc[2 * k]);
            acc[2 * k + 1] = fmaf(w1, f1.y, acc[2 * k + 1]);
        }
    }
    if (p < pend) {
        int c0 = col[p];
        uint4 r0 = *reinterpret_cast<const uint4*>(&h[(size_t)c0 * 64 + fl]);
        float w0 = dinv[c0];
        const unsigned* u0 = &r0.x;
#pragma unroll
        for (int k = 0; k < 4; ++k) {
            float2 f0 = __half22float2(*reinterpret_cast<const __half2*>(&u0[k]));
            acc[2 * k]     = fmaf(w0, f0.x, acc[2 * k]);
            acc[2 * k + 1] = fmaf(w0, f0.y, acc[2 * k + 1]);
        }
    }
#pragma unroll
    for (int j = 0; j < 8; ++j) {
        acc[j] += __shfl_xor(acc[j], 8, 64);
        acc[j] += __shfl_xor(acc[j], 16, 64);
        acc[j] += __shfl_xor(acc[j], 32, 64);
    }
    if (g == 0) {                     // lanes 0..7 own the epilogue
        float di = dinv[node];
        uint4 sv = *reinterpret_cast<const uint4*>(&h[(size_t)node * 64 + fl]);
        const unsigned* su = &sv.x;
        float v[8];
#pragma unroll
        for (int k = 0; k < 4; ++k) {
            float2 f = __half22float2(*reinterpret_cast<const __half2*>(&su[k]));
            v[2 * k]     = fmaf(di, f.x, acc[2 * k]) * di;
            v[2 * k + 1] = fmaf(di, f.y, acc[2 * k + 1]) * di;
        }
        if (bias) {
            float4 b0 = *reinterpret_cast<const float4*>(&bias[fl]);
            float4 b1 = *reinterpret_cast<const float4*>(&bias[fl + 4]);
            v[0] += b0.x; v[1] += b0.y; v[2] += b0.z; v[3] += b0.w;
            v[4] += b1.x; v[5] += b1.y; v[6] += b1.z; v[7] += b1.w;
        }
        if (relu) {
#pragma unroll
            for (int j = 0; j < 8; ++j) v[j] = fmaxf(v[j], 0.f);
        }
        __half hv[8];
#pragma unroll
        for (int j = 0; j < 8; ++j) hv[j] = __float2half(v[j]);
        *reinterpret_cast<uint4*>(&out[(size_t)node * 64 + fl]) =
            *reinterpret_cast<const uint4*>(hv);
    }
}

// ---------------- GEMM2 via MFMA: fp16 [M,64] @ [64,128] + b -> fp32 [M,128] ----------------
__global__ __launch_bounds__(256) void gemm2_kernel(const __half* __restrict__ A,
                                                    const __half* __restrict__ wf,
                                                    const float* __restrict__ bias,
                                                    float* __restrict__ out, int M) {
    int tid = threadIdx.x;
    int w = tid >> 6;
    int l = tid & 63;
    int lrow = l & 15;
    int lk   = l >> 4;
    int base = blockIdx.x * 64 + w * 16;
    int arow = base + lrow; if (arow >= M) arow = M - 1;
    f16x8 a0 = *reinterpret_cast<const f16x8*>(&A[(size_t)arow * 64 + lk * 8]);
    f16x8 a1 = *reinterpret_cast<const f16x8*>(&A[(size_t)arow * 64 + 32 + lk * 8]);
    const f16x8* wf8 = reinterpret_cast<const f16x8*>(wf);
    f32x4 acc[8] = {};
#pragma unroll
    for (int nb = 0; nb < 8; ++nb) {
        acc[nb] = __builtin_amdgcn_mfma_f32_16x16x32_f16(a0, wf8[nb * 64 + l], acc[nb], 0, 0, 0);
        acc[nb] = __builtin_amdgcn_mfma_f32_16x16x32_f16(a1, wf8[(8 + nb) * 64 + l], acc[nb], 0, 0, 0);
    }
#pragma unroll
    for (int nb = 0; nb < 8; ++nb) {
        float bv = bias[nb * 16 + lrow];
#pragma unroll
        for (int r = 0; r < 4; ++r) {
            int row = base + lk * 4 + r;
            if (row < M) out[(size_t)row * 128 + nb * 16 + lrow] = acc[nb][r] + bv;
        }
    }
}

extern "C" void kernel_launch(void* const* d_in, const int* in_sizes, int n_in,
                              void* d_out, int out_size, void* d_ws, size_t ws_size,
                              hipStream_t stream) {
    const float* x  = (const float*)d_in[0];
    const int*   ei = (const int*)d_in[1];
    const float* W1 = (const float*)d_in[2];
    const float* b1 = (const float*)d_in[3];
    const float* W2 = (const float*)d_in[4];
    const float* b2 = (const float*)d_in[5];
    float* out = (float*)d_out;
    const int n = NNODES;
    const int E = in_sizes[1] / 2;
    const int CE = (E + NB_CHUNK - 1) / NB_CHUNK;

    char* w = (char*)d_ws;
    auto alloc = [&](size_t bytes) {
        char* p = w;
        w += (bytes + 255) & ~(size_t)255;
        return p;
    };
    int*    flag   = (int*)   alloc(4);
    int*    src32  = (int*)   alloc((size_t)E * 4);
    int*    dst32  = (int*)   alloc((size_t)E * 4);
    int*    counts = (int*)   alloc((size_t)NC * 4);
    int*    cbase  = (int*)   alloc((size_t)(NC + 1) * 4);
    float*  dinv   = (float*) alloc((size_t)n * 4);
    int*    ptr    = (int*)   alloc((size_t)(n + 1) * 4);
    int*    cw     = (int*)   alloc((size_t)E * 4);
    int*    col    = (int*)   alloc((size_t)E * 4);
    __half* wfrag  = (__half*)alloc(16384 * 2);
    __half* wfrag2 = (__half*)alloc(8192 * 2);
    __half* H1     = (__half*)alloc((size_t)n * 64 * 2);
    __half* h1     = (__half*)alloc((size_t)n * 64 * 2);
    __half* A2     = (__half*)alloc((size_t)n * 64 * 2);

    int sbC = (NC + SCAN_ELEMS - 1) / SCAN_ELEMS;   // 98 scanw blocks
    int g1b = (n + 63) / 64;                        // 1563 gemm1 blocks

    prep_kernel<<<97, 256, 0, stream>>>(W1, W2, ei, wfrag, wfrag2, flag, cbase, E);
    convert_gemm1_kernel<<<NB_CHUNK + g1b, 256, 0, stream>>>(
        ei, src32, dst32, counts, E, CE, flag, x, wfrag, H1, n);
    scanw_kernel<<<sbC, 256, 0, stream>>>(counts, cbase, NC);
    scatter_kernel<<<NB_CHUNK, 256, 0, stream>>>(src32, dst32, cbase, cw, E, CE);
    bucketfin_kernel<<<NBUCK, 256, 0, stream>>>(cw, cbase, ptr, dinv, col, n, E);

    aggregate_kernel<<<(n + 3) / 4, 256, 0, stream>>>(H1, ptr, col, dinv, b1, h1, n, 1);
    aggregate_kernel<<<(n + 3) / 4, 256, 0, stream>>>(h1, ptr, col, dinv, nullptr, A2, n, 0);
    gemm2_kernel<<<(n + 63) / 64, 256, 0, stream>>>(A2, wfrag2, b2, out, n);
}

// Round 20
// 178.021 us; speedup vs baseline: 2.6001x; 1.0683x over previous
//
#include <hip/hip_runtime.h>
#include <hip/hip_fp16.h>

#define NNODES 100000
#define NBUCK 391                 // ceil(100000/256) buckets of 256 nodes (dst>>8)
#define NB_CHUNK 256              // edge chunks for counting sort
#define NC (NBUCK * NB_CHUNK)     // count-matrix size = 100096
#define SCAN_ELEMS 1024           // elements per scan block (256 threads x 4)

typedef _Float16 f16x8 __attribute__((ext_vector_type(8)));
typedef float    f32x4 __attribute__((ext_vector_type(4)));

// ---------------- K0: W-fragment prep + edge dtype sniffer, one launch ----------------
__global__ __launch_bounds__(256) void prep_kernel(const float* __restrict__ W1,
                                                   const float* __restrict__ W2,
                                                   const int* __restrict__ raw,
                                                   __half* __restrict__ wf1,
                                                   __half* __restrict__ wf2,
                                                   int* __restrict__ flag) {
    int b = blockIdx.x;
    if (b < 64) {
        int flat = b * 256 + threadIdx.x;         // W1 frags
        int j  = flat & 7;
        int l  = (flat >> 3) & 63;
        int nb = (flat >> 9) & 3;
        int kc = flat >> 11;
        int k  = kc * 32 + ((l >> 4) << 3) + j;
        int nc = nb * 16 + (l & 15);
        wf1[flat] = __float2half(W1[k * 64 + nc]);
    } else if (b < 96) {
        int flat = (b - 64) * 256 + threadIdx.x;  // W2 frags
        int j  = flat & 7;
        int l  = (flat >> 3) & 63;
        int nb = (flat >> 9) & 7;
        int kc = flat >> 12;
        int k  = kc * 32 + ((l >> 4) << 3) + j;
        int nc = nb * 16 + (l & 15);
        wf2[flat] = __float2half(W2[k * 128 + nc]);
    } else {
        __shared__ int cnt;
        if (threadIdx.x == 0) cnt = 0;
        __syncthreads();
        if (threadIdx.x < 100) {
            if (raw[2 * threadIdx.x + 1] == 0) atomicAdd(&cnt, 1);
        }
        __syncthreads();
        if (threadIdx.x == 0) *flag = (cnt > 50) ? 1 : 0;
    }
}

// ---------------- K1: fused [convert+count  ||  gemm1 MFMA, K-split tiles] ----------------
// gemm1 stages x in TWO 64x128 k-tiles (xs[64][136], 17.4KB LDS) -> 8 blocks/CU
// instead of 4 (R19 diagnosis: K1 was latency-bound at 34.7% occupancy).
__global__ __launch_bounds__(256) void convert_gemm1_kernel(const int* __restrict__ raw,
                                                            int* __restrict__ src32,
                                                            int* __restrict__ dst32,
                                                            int* __restrict__ counts,
                                                            int E, int CE,
                                                            const int* __restrict__ flag,
                                                            const float* __restrict__ x,
                                                            const __half* __restrict__ wf,
                                                            __half* __restrict__ H, int M) {
    __shared__ __align__(16) char smem[64 * 136 * 2];   // union: hist[391] | xs[64][136]
    int bid = blockIdx.x;
    if (bid < NB_CHUNK) {
        int* hist = (int*)smem;
        for (int i = threadIdx.x; i < NBUCK; i += 256) hist[i] = 0;
        __syncthreads();
        int isI64 = *flag;
        int beg = bid * CE;
        int end = beg + CE; if (end > E) end = E;
        const int2* raw2 = reinterpret_cast<const int2*>(raw);
        for (int e = beg + (int)threadIdx.x; e < end; e += 256) {
            int s, d;
            if (isI64) {
                s = raw2[e].x;          // raw[2e]   (low word)
                d = raw2[E + e].x;      // raw[2E+2e]
            } else {
                s = raw[e];
                d = raw[E + e];
            }
            src32[e] = s;
            dst32[e] = d;
            atomicAdd(&hist[d >> 8], 1);              // LDS atomic
        }
        __syncthreads();
        for (int k = threadIdx.x; k < NBUCK; k += 256)
            counts[k * NB_CHUNK + bid] = hist[k];     // bucket-major for linear scan
    } else {
        __half (*xs)[136] = (__half(*)[136])smem;     // 272B row stride: 16B-aligned,
        int tid = threadIdx.x;                        // bank offset 4/row -> 2-way (free)
        int bm = (bid - NB_CHUNK) * 64;
        const float4* x4 = reinterpret_cast<const float4*>(x);
        int w = tid >> 6;          // wave 0..3 -> rows bm+w*16 .. +15
        int l = tid & 63;
        int lrow = l & 15;
        int lk   = l >> 4;
        const f16x8* wf8 = reinterpret_cast<const f16x8*>(wf);
        f32x4 acc[4] = {};
        for (int kt = 0; kt < 2; ++kt) {              // two k-tiles of 128
#pragma unroll
            for (int i = 0; i < 8; ++i) {             // stage: 2048 float4 / 256 thr
                int lin = i * 256 + tid;
                int row = lin >> 5;                   // 0..63
                int c4  = lin & 31;                   // float4 within k-tile
                int gr = bm + row; if (gr >= M) gr = M - 1;
                float4 v = x4[(size_t)gr * 64 + kt * 32 + c4];
                __half* dst = &xs[row][c4 * 4];
                dst[0] = __float2half(v.x); dst[1] = __float2half(v.y);
                dst[2] = __float2half(v.z); dst[3] = __float2half(v.w);
            }
            __syncthreads();
#pragma unroll
            for (int kci = 0; kci < 4; ++kci) {
                f16x8 a = *reinterpret_cast<const f16x8*>(&xs[w * 16 + lrow][kci * 32 + lk * 8]);
                int kc = kt * 4 + kci;
#pragma unroll
                for (int nb = 0; nb < 4; ++nb) {
                    f16x8 bfr = wf8[(kc * 4 + nb) * 64 + l];
                    acc[nb] = __builtin_amdgcn_mfma_f32_16x16x32_f16(a, bfr, acc[nb], 0, 0, 0);
                }
            }
            __syncthreads();
        }
#pragma unroll
        for (int nb = 0; nb < 4; ++nb)
#pragma unroll
            for (int r = 0; r < 4; ++r) {
                int row = bm + w * 16 + lk * 4 + r;
                if (row < M) H[(size_t)row * 64 + nb * 16 + lrow] = __float2half(acc[nb][r]);
            }
    }
}

// ---------------- device-wide exclusive scan (counts -> cbase), 3 kernels ----------------
__global__ __launch_bounds__(256) void scan_partial_kernel(const int* __restrict__ in,
                                                           int* __restrict__ bsum, int n) {
    int base = blockIdx.x * SCAN_ELEMS + threadIdx.x * 4;
    int s = 0;
    if (base + 3 < n) {
        int4 v = *reinterpret_cast<const int4*>(&in[base]);
        s = v.x + v.y + v.z + v.w;
    } else {
        for (int i = base; i < n && i < base + 4; ++i) s += in[i];
    }
#pragma unroll
    for (int d = 32; d; d >>= 1) s += __shfl_down(s, d, 64);
    __shared__ int ws[4];
    int wid = threadIdx.x >> 6;
    if ((threadIdx.x & 63) == 0) ws[wid] = s;
    __syncthreads();
    if (threadIdx.x == 0) bsum[blockIdx.x] = ws[0] + ws[1] + ws[2] + ws[3];
}

__global__ void scan_partials_kernel(const int* __restrict__ bsum, int* __restrict__ boff,
                                     int* __restrict__ total_out, int nb) {
    __shared__ int s[128];
    int t = threadIdx.x;
    s[t] = (t < nb) ? bsum[t] : 0;
    __syncthreads();
    for (int d = 1; d < 128; d <<= 1) {
        int v = (t >= d) ? s[t - d] : 0;
        __syncthreads();
        s[t] += v;
        __syncthreads();
    }
    if (t < nb) boff[t] = (t == 0) ? 0 : s[t - 1];
    if (t == 127) *total_out = s[127];
}

__global__ __launch_bounds__(256) void scan_write_kernel(const int* __restrict__ in,
                                                         const int* __restrict__ boff,
                                                         int* __restrict__ outp, int n) {
    __shared__ int ts[256];
    int base = blockIdx.x * SCAN_ELEMS + threadIdx.x * 4;
    int v0 = 0, v1 = 0, v2 = 0, v3 = 0;
    if (base + 3 < n) {
        int4 v = *reinterpret_cast<const int4*>(&in[base]);
        v0 = v.x; v1 = v.y; v2 = v.z; v3 = v.w;
    } else {
        if (base < n)     v0 = in[base];
        if (base + 1 < n) v1 = in[base + 1];
        if (base + 2 < n) v2 = in[base + 2];
    }
    ts[threadIdx.x] = v0 + v1 + v2 + v3;
    __syncthreads();
    for (int d = 1; d < 256; d <<= 1) {
        int t = (threadIdx.x >= d) ? ts[threadIdx.x - d] : 0;
        __syncthreads();
        ts[threadIdx.x] += t;
        __syncthreads();
    }
    int run = boff[blockIdx.x] + ((threadIdx.x == 0) ? 0 : ts[threadIdx.x - 1]);
    if (base < n)     { outp[base] = run;     run += v0; }
    if (base + 1 < n) { outp[base + 1] = run; run += v1; }
    if (base + 2 < n) { outp[base + 2] = run; run += v2; }
    if (base + 3 < n) { outp[base + 3] = run; }
}

// ---------------- counting sort pass 2: scatter (packed: src | (d&255)<<24) ----------------
__global__ __launch_bounds__(256) void scatter_kernel(const int* __restrict__ src32,
                                                      const int* __restrict__ dst32,
                                                      const int* __restrict__ cbase,
                                                      int* __restrict__ cw,
                                                      int E, int CE) {
    __shared__ int cur[NBUCK];
    int b = blockIdx.x;
    for (int k = threadIdx.x; k < NBUCK; k += 256)
        cur[k] = cbase[k * NB_CHUNK + b];
    __syncthreads();
    int beg = b * CE;
    int end = beg + CE; if (end > E) end = E;
    for (int e = beg + (int)threadIdx.x; e < end; e += 256) {
        int s = src32[e];
        int d = dst32[e];
        int pos = atomicAdd(&cur[d >> 8], 1);     // LDS atomic
        cw[pos] = s | ((d & 255) << 24);          // single-CU contiguous run per bucket
    }
}

// ---------------- bucketfin: histdeg + dinv + ptr (bucket-local scan) + col fill ----------------
__global__ __launch_bounds__(256) void bucketfin_kernel(const int* __restrict__ cw,
                                                        const int* __restrict__ cbase,
                                                        int* __restrict__ ptr,
                                                        float* __restrict__ dinv,
                                                        int* __restrict__ col,
                                                        int n, int E) {
    __shared__ int hist[256];
    __shared__ int sc[256];
    int tid = threadIdx.x;
    int k = blockIdx.x;
    hist[tid] = 0;
    __syncthreads();
    int beg = cbase[k * NB_CHUNK];
    int end = cbase[(k + 1) * NB_CHUNK];
    for (int e = beg + tid; e < end; e += 256)
        atomicAdd(&hist[(cw[e] >> 24) & 255], 1); // LDS atomic
    __syncthreads();
    int dg = hist[tid];
    sc[tid] = dg;
    __syncthreads();
    for (int d = 1; d < 256; d <<= 1) {           // Hillis-Steele inclusive scan
        int t = (tid >= d) ? sc[tid - d] : 0;
        __syncthreads();
        sc[tid] += t;
        __syncthreads();
    }
    int p0 = beg + sc[tid] - dg;                  // bucket base + exclusive prefix
    int i = (k << 8) + tid;
    if (i < n) {
        ptr[i] = p0;
        dinv[i] = rsqrtf((float)(dg + 1));        // +1 self loop; always > 0
    }
    if (k == NBUCK - 1 && tid == 0) ptr[n] = E;
    __syncthreads();
    hist[tid] = p0;                               // reuse as cursor
    __syncthreads();
    for (int e = beg + tid; e < end; e += 256) {
        int v = cw[e];
        int pos = atomicAdd(&hist[(v >> 24) & 255], 1);
        col[pos] = v & 0x00FFFFFF;
    }
}

// ---------------- aggregation: fp16 gathers, per-edge weight dinv[col] ----------------
__global__ __launch_bounds__(256) void aggregate_kernel(const __half* __restrict__ h,
                                                        const int* __restrict__ ptr,
                                                        const int* __restrict__ col,
                                                        const float* __restrict__ dinv,
                                                        const float* __restrict__ bias,
                                                        __half* __restrict__ out, int n,
                                                        int relu) {
    int node = (blockIdx.x << 2) + (threadIdx.x >> 6);
    if (node >= n) return;
    int lane = threadIdx.x & 63;
    int g  = lane >> 3;               // edge-group 0..7
    int fl = (lane & 7) << 3;         // feature base: 0,8,...,56
    float acc[8] = {};
    int pend = ptr[node + 1];
    int p = ptr[node] + g;
    for (; p + 8 < pend; p += 16) {   // unroll 2: 16 edges in flight per wave
        int c0 = col[p];
        int c1 = col[p + 8];
        uint4 r0 = *reinterpret_cast<const uint4*>(&h[(size_t)c0 * 64 + fl]);
        uint4 r1 = *reinterpret_cast<const uint4*>(&h[(size_t)c1 * 64 + fl]);
        float w0 = dinv[c0], w1 = dinv[c1];
        const unsigned* u0 = &r0.x;
        const unsigned* u1 = &r1.x;
#pragma unroll
        for (int k = 0; k < 4; ++k) {
            float2 f0 = __half22float2(*reinterpret_cast<const __half2*>(&u0[k]));
            float2 f1 = __half22float2(*reinterpret_cast<const __half2*>(&u1[k]));
            acc[2 * k]     = fmaf(w0, f0.x, acc[2 * k]);
            acc[2 * k + 1] = fmaf(w0, f0.y, acc[2 * k + 1]);
            acc[2 * k]     = fmaf(w1, f1.x, acc[2 * k]);
            acc[2 * k + 1] = fmaf(w1, f1.y, acc[2 * k + 1]);
        }
    }
    if (p < pend) {
        int c0 = col[p];
        uint4 r0 = *reinterpret_cast<const uint4*>(&h[(size_t)c0 * 64 + fl]);
        float w0 = dinv[c0];
        const unsigned* u0 = &r0.x;
#pragma unroll
        for (int k = 0; k < 4; ++k) {
            float2 f0 = __half22float2(*reinterpret_cast<const __half2*>(&u0[k]));
            acc[2 * k]     = fmaf(w0, f0.x, acc[2 * k]);
            acc[2 * k + 1] = fmaf(w0, f0.y, acc[2 * k + 1]);
        }
    }
#pragma unroll
    for (int j = 0; j < 8; ++j) {
        acc[j] += __shfl_xor(acc[j], 8, 64);
        acc[j] += __shfl_xor(acc[j], 16, 64);
        acc[j] += __shfl_xor(acc[j], 32, 64);
    }
    if (g == 0) {                     // lanes 0..7 own the epilogue
        float di = dinv[node];
        uint4 sv = *reinterpret_cast<const uint4*>(&h[(size_t)node * 64 + fl]);
        const unsigned* su = &sv.x;
        float v[8];
#pragma unroll
        for (int k = 0; k < 4; ++k) {
            float2 f = __half22float2(*reinterpret_cast<const __half2*>(&su[k]));
            v[2 * k]     = fmaf(di, f.x, acc[2 * k]) * di;
            v[2 * k + 1] = fmaf(di, f.y, acc[2 * k + 1]) * di;
        }
        if (bias) {
            float4 b0 = *reinterpret_cast<const float4*>(&bias[fl]);
            float4 b1 = *reinterpret_cast<const float4*>(&bias[fl + 4]);
            v[0] += b0.x; v[1] += b0.y; v[2] += b0.z; v[3] += b0.w;
            v[4] += b1.x; v[5] += b1.y; v[6] += b1.z; v[7] += b1.w;
        }
        if (relu) {
#pragma unroll
            for (int j = 0; j < 8; ++j) v[j] = fmaxf(v[j], 0.f);
        }
        __half hv[8];
#pragma unroll
        for (int j = 0; j < 8; ++j) hv[j] = __float2half(v[j]);
        *reinterpret_cast<uint4*>(&out[(size_t)node * 64 + fl]) =
            *reinterpret_cast<const uint4*>(hv);
    }
}

// ---------------- GEMM2 via MFMA: fp16 [M,64] @ [64,128] + b -> fp32 [M,128] ----------------
__global__ __launch_bounds__(256) void gemm2_kernel(const __half* __restrict__ A,
                                                    const __half* __restrict__ wf,
                                                    const float* __restrict__ bias,
                                                    float* __restrict__ out, int M) {
    int tid = threadIdx.x;
    int w = tid >> 6;
    int l = tid & 63;
    int lrow = l & 15;
    int lk   = l >> 4;
    int base = blockIdx.x * 64 + w * 16;
    int arow = base + lrow; if (arow >= M) arow = M - 1;
    f16x8 a0 = *reinterpret_cast<const f16x8*>(&A[(size_t)arow * 64 + lk * 8]);
    f16x8 a1 = *reinterpret_cast<const f16x8*>(&A[(size_t)arow * 64 + 32 + lk * 8]);
    const f16x8* wf8 = reinterpret_cast<const f16x8*>(wf);
    f32x4 acc[8] = {};
#pragma unroll
    for (int nb = 0; nb < 8; ++nb) {
        acc[nb] = __builtin_amdgcn_mfma_f32_16x16x32_f16(a0, wf8[nb * 64 + l], acc[nb], 0, 0, 0);
        acc[nb] = __builtin_amdgcn_mfma_f32_16x16x32_f16(a1, wf8[(8 + nb) * 64 + l], acc[nb], 0, 0, 0);
    }
#pragma unroll
    for (int nb = 0; nb < 8; ++nb) {
        float bv = bias[nb * 16 + lrow];
#pragma unroll
        for (int r = 0; r < 4; ++r) {
            int row = base + lk * 4 + r;
            if (row < M) out[(size_t)row * 128 + nb * 16 + lrow] = acc[nb][r] + bv;
        }
    }
}

extern "C" void kernel_launch(void* const* d_in, const int* in_sizes, int n_in,
                              void* d_out, int out_size, void* d_ws, size_t ws_size,
                              hipStream_t stream) {
    const float* x  = (const float*)d_in[0];
    const int*   ei = (const int*)d_in[1];
    const float* W1 = (const float*)d_in[2];
    const float* b1 = (const float*)d_in[3];
    const float* W2 = (const float*)d_in[4];
    const float* b2 = (const float*)d_in[5];
    float* out = (float*)d_out;
    const int n = NNODES;
    const int E = in_sizes[1] / 2;
    const int CE = (E + NB_CHUNK - 1) / NB_CHUNK;

    char* w = (char*)d_ws;
    auto alloc = [&](size_t bytes) {
        char* p = w;
        w += (bytes + 255) & ~(size_t)255;
        return p;
    };
    int*    flag   = (int*)   alloc(4);
    int*    src32  = (int*)   alloc((size_t)E * 4);
    int*    dst32  = (int*)   alloc((size_t)E * 4);
    int*    counts = (int*)   alloc((size_t)NC * 4);
    int*    cbase  = (int*)   alloc((size_t)(NC + 1) * 4);
    float*  dinv   = (float*) alloc((size_t)n * 4);
    int*    ptr    = (int*)   alloc((size_t)(n + 1) * 4);
    int*    bsum   = (int*)   alloc(128 * 4);
    int*    boff   = (int*)   alloc(128 * 4);
    int*    cw     = (int*)   alloc((size_t)E * 4);
    int*    col    = (int*)   alloc((size_t)E * 4);
    __half* wfrag  = (__half*)alloc(16384 * 2);
    __half* wfrag2 = (__half*)alloc(8192 * 2);
    __half* H1     = (__half*)alloc((size_t)n * 64 * 2);
    __half* h1     = (__half*)alloc((size_t)n * 64 * 2);
    __half* A2     = (__half*)alloc((size_t)n * 64 * 2);

    int sbC = (NC + SCAN_ELEMS - 1) / SCAN_ELEMS;   // 98
    int g1b = (n + 63) / 64;                        // 1563 gemm1 blocks

    prep_kernel<<<97, 256, 0, stream>>>(W1, W2, ei, wfrag, wfrag2, flag);
    convert_gemm1_kernel<<<NB_CHUNK + g1b, 256, 0, stream>>>(
        ei, src32, dst32, counts, E, CE, flag, x, wfrag, H1, n);
    scan_partial_kernel<<<sbC, 256, 0, stream>>>(counts, bsum, NC);
    scan_partials_kernel<<<1, 128, 0, stream>>>(bsum, boff, &cbase[NC], sbC);
    scan_write_kernel<<<sbC, 256, 0, stream>>>(counts, boff, cbase, NC);
    scatter_kernel<<<NB_CHUNK, 256, 0, stream>>>(src32, dst32, cbase, cw, E, CE);
    bucketfin_kernel<<<NBUCK, 256, 0, stream>>>(cw, cbase, ptr, dinv, col, n, E);

    aggregate_kernel<<<(n + 3) / 4, 256, 0, stream>>>(H1, ptr, col, dinv, b1, h1, n, 1);
    aggregate_kernel<<<(n + 3) / 4, 256, 0, stream>>>(h1, ptr, col, dinv, nullptr, A2, n, 0);
    gemm2_kernel<<<(n + 63) / 64, 256, 0, stream>>>(A2, wfrag2, b2, out, n);
}